// Round 8
// baseline (5389.450 us; speedup 1.0000x reference)
//
#include <hip/hip_runtime.h>
#include <stdint.h>

typedef float  f32x4 __attribute__((ext_vector_type(4)));
typedef short  s16x8 __attribute__((ext_vector_type(8)));
typedef unsigned int u32;
typedef unsigned long long u64;
typedef unsigned short bfu;
typedef long long i64;

#define B_ 256
#define T_ 256
#define I_ 128
#define H_ 512
#define O_ 128
#define CH 16
#define NCH (T_ / CH)
#define SLOTS ((size_t)CH * B_ * H_)   // elems per bf16 pre-array

__device__ __forceinline__ bfu f2b(float f) {
    u32 u = __float_as_uint(f);
    u += 0x7fffu + ((u >> 16) & 1u);
    return (bfu)(u >> 16);
}
__device__ __forceinline__ float b2f(bfu b) { return __uint_as_float(((u32)b) << 16); }
__device__ __forceinline__ float sigf(float x) { return 1.f / (1.f + __expf(-x)); }
__device__ __forceinline__ float tanhfast(float x) { return 1.f - 2.f / (__expf(2.f * x) + 1.f); }
__device__ __forceinline__ u64 pk2(float a, float b) {
    return (u64)__float_as_uint(a) | ((u64)__float_as_uint(b) << 32);
}
__device__ __forceinline__ float lo2(u64 v) { return __uint_as_float((u32)v); }
__device__ __forceinline__ float hi2(u64 v) { return __uint_as_float((u32)(v >> 32)); }

// software float -> OCP e4m3fn, RNE, saturating
__device__ __forceinline__ unsigned char f2e4m3(float f) {
    u32 u = __float_as_uint(f);
    u32 s = (u >> 24) & 0x80u;
    u &= 0x7fffffffu;
    if (u >= 0x43e00000u) return (unsigned char)(s | 0x7eu);    // >= 448 -> sat
    if (u < 0x3c800000u) {                                       // < 2^-6 -> subnormal
        int m = __float2int_rn(__uint_as_float(u) * 512.f);
        if (m >= 8) return (unsigned char)(s | 0x08u);
        return (unsigned char)(s | (u32)m);
    }
    u += 0x7ffffu + ((u >> 20) & 1u);                            // RNE at bit 20
    u32 e8 = ((u >> 23) & 0xffu) - 120u;                         // bias 127 -> 7
    return (unsigned char)(s | (e8 << 3) | ((u >> 20) & 7u));
}

// ===========================================================================
// k_pack: weights -> MFMA B-fragment order.
// frag 16x16x32: lane L holds B[k = kt*32 + (L>>4)*8 + j][n = nt*16 + (L&15)].
// PW bf16 (W|V per gate), PG bf16 (Wgh), PUc bf16 (Uc), PU8 fp8 (Uz,Ur x32).
// ===========================================================================
__global__ __launch_bounds__(256) void k_pack(
    const float* __restrict__ Wz, const float* __restrict__ Wr, const float* __restrict__ Wc,
    const float* __restrict__ Vz, const float* __restrict__ Vr, const float* __restrict__ Vc,
    const float* __restrict__ Wgh,
    const float* __restrict__ Uz, const float* __restrict__ Ur, const float* __restrict__ Uc,
    short* __restrict__ PW, short* __restrict__ PG, short* __restrict__ PUc,
    unsigned char* __restrict__ PU8)
{
    int wv = blockIdx.x * 4 + (threadIdx.x >> 6);
    int L = threadIdx.x & 63;
    if (wv >= 2432) return;
    int koff = (L >> 4) << 3;
    int ncol;
    if (wv < 768) {                       // PW: gate x (kt<4:W, kt>=4:V)
        int g = wv >> 8, rem = wv & 255;
        int kt = rem >> 5; ncol = (rem & 31) * 16 + (L & 15);
        const float* src = (kt < 4) ? (g == 0 ? Wz : g == 1 ? Wr : Wc)
                                    : (g == 0 ? Vz : g == 1 ? Vr : Vc);
        int kbase = (kt & 3) * 32 + koff;
        s16x8 v;
        #pragma unroll
        for (int j = 0; j < 8; ++j) v[j] = (short)f2b(src[(kbase + j) * H_ + ncol]);
        *(s16x8*)&PW[((size_t)(g * 256 + rem) * 64 + L) * 8] = v;
    } else if (wv < 896) {                // PG
        int rem = wv - 768;
        ncol = (rem & 31) * 16 + (L & 15);
        int kbase = (rem >> 5) * 32 + koff;
        s16x8 v;
        #pragma unroll
        for (int j = 0; j < 8; ++j) v[j] = (short)f2b(Wgh[(kbase + j) * H_ + ncol]);
        *(s16x8*)&PG[((size_t)rem * 64 + L) * 8] = v;
    } else if (wv < 1408) {               // PUc bf16
        int rem = wv - 896;               // kt*32+nt, kt 0..15
        ncol = (rem & 31) * 16 + (L & 15);
        int kbase = (rem >> 5) * 32 + koff;
        s16x8 v;
        #pragma unroll
        for (int j = 0; j < 8; ++j) v[j] = (short)f2b(Uc[(kbase + j) * H_ + ncol]);
        *(s16x8*)&PUc[((size_t)rem * 64 + L) * 8] = v;
    } else {                              // PU8: Uz, Ur scaled x32, e4m3
        int rem = wv - 1408;              // g*512 + kt*32 + nt
        int g = rem >> 9, r2 = rem & 511;
        ncol = (r2 & 31) * 16 + (L & 15);
        int kbase = (r2 >> 5) * 32 + koff;
        const float* src = (g == 0) ? Uz : Ur;
        unsigned char* d = PU8 + ((size_t)rem * 64 + L) * 8;
        #pragma unroll
        for (int j = 0; j < 8; ++j) d[j] = f2e4m3(src[(kbase + j) * H_ + ncol] * 32.f);
    }
}

// ===========================================================================
// k1 unit: input-side projections for one batch row b, 16 timesteps.
// 512 threads (8 waves x 64 cols). bf16 outputs, layout [tl][b][H].
// ===========================================================================
__device__ void k1_unit(char* sm, int b, int t0,
    const float* __restrict__ x, const float* __restrict__ dl,
    const float* __restrict__ mk, const float* __restrict__ xf,
    const float* __restrict__ bz, const float* __restrict__ br, const float* __restrict__ bc,
    const float* __restrict__ Bgh,
    const float* __restrict__ Wgx, const float* __restrict__ Bgx,
    const short* __restrict__ PW, const short* __restrict__ PG,
    bfu* __restrict__ pz, bfu* __restrict__ pr, bfu* __restrict__ pc, bfu* __restrict__ gm)
{
    short* Abuf = (short*)sm;             // 12 KB: [kt 0..11][lane][8]
    const int t = threadIdx.x & 511;
    const int L = t & 63, w = t >> 6;

    for (int cc = t; cc < 12 * 64; cc += 512) {
        int Ls = cc & 63, kt = cc >> 6;
        int tl = Ls & 15, q = Ls >> 4;
        int gbase = (b * T_ + t0 + tl) * I_;
        s16x8 v;
        if (kt < 4) {
            int kb = kt * 32 + q * 8;
            f32x4 m0 = *(const f32x4*)&mk[gbase + kb], m1 = *(const f32x4*)&mk[gbase + kb + 4];
            f32x4 d0 = *(const f32x4*)&dl[gbase + kb], d1 = *(const f32x4*)&dl[gbase + kb + 4];
            f32x4 f0 = *(const f32x4*)&xf[gbase + kb], f1 = *(const f32x4*)&xf[gbase + kb + 4];
            f32x4 x0 = *(const f32x4*)&x[gbase + kb],  x1 = *(const f32x4*)&x[gbase + kb + 4];
            #pragma unroll
            for (int j = 0; j < 8; ++j) {
                int k = kb + j;
                float mv = (j < 4) ? m0[j] : m1[j - 4];
                float dv = (j < 4) ? d0[j] : d1[j - 4];
                float fv = (j < 4) ? f0[j] : f1[j - 4];
                float xv = (j < 4) ? x0[j] : x1[j - 4];
                float dx = dv * Wgx[k] + Bgx[k];
                float xr = dx * fv + (1.f - dx) * 0.001f;
                v[j] = (short)f2b((mv > 0.5f) ? xr : xv);
            }
        } else if (kt < 8) {
            int kb = (kt - 4) * 32 + q * 8;
            f32x4 m0 = *(const f32x4*)&mk[gbase + kb], m1 = *(const f32x4*)&mk[gbase + kb + 4];
            #pragma unroll
            for (int j = 0; j < 8; ++j) v[j] = (short)f2b(1.f - ((j < 4) ? m0[j] : m1[j - 4]));
        } else {
            int kb = (kt - 8) * 32 + q * 8;
            f32x4 m0 = *(const f32x4*)&mk[gbase + kb], m1 = *(const f32x4*)&mk[gbase + kb + 4];
            #pragma unroll
            for (int j = 0; j < 8; ++j) v[j] = (short)f2b((j < 4) ? m0[j] : m1[j - 4]);
        }
        *(s16x8*)&Abuf[(size_t)cc * 8] = v;
    }
    __syncthreads();

    const s16x8* PWf = (const s16x8*)PW;
    const s16x8* PGf = (const s16x8*)PG;

    for (int g = 0; g < 3; ++g) {
        f32x4 acc[4];
        #pragma unroll
        for (int nt = 0; nt < 4; ++nt) acc[nt] = (f32x4)0.f;
        for (int kt = 0; kt < 8; ++kt) {
            s16x8 a = *(const s16x8*)&Abuf[(kt * 64 + L) * 8];
            const s16x8* pw = PWf + ((size_t)(g * 256 + kt * 32 + w * 4) * 64 + L);
            #pragma unroll
            for (int nt = 0; nt < 4; ++nt)
                acc[nt] = __builtin_amdgcn_mfma_f32_16x16x32_bf16(a, pw[(size_t)nt * 64], acc[nt], 0, 0, 0);
        }
        const float* bias = (g == 0) ? bz : (g == 1) ? br : bc;
        bfu* dst = (g == 0) ? pz : (g == 1) ? pr : pc;
        #pragma unroll
        for (int nt = 0; nt < 4; ++nt) {
            int n = w * 64 + nt * 16 + (L & 15);
            float bv = bias[n];
            #pragma unroll
            for (int reg = 0; reg < 4; ++reg) {
                int tl = (L >> 4) * 4 + reg;
                dst[(size_t)(tl * B_ + b) * H_ + n] = f2b(acc[nt][reg] + bv);
            }
        }
    }
    {
        f32x4 acc[4];
        #pragma unroll
        for (int nt = 0; nt < 4; ++nt) acc[nt] = (f32x4)0.f;
        for (int kk = 0; kk < 4; ++kk) {
            s16x8 a = *(const s16x8*)&Abuf[((8 + kk) * 64 + L) * 8];
            const s16x8* pg = PGf + ((size_t)(kk * 32 + w * 4) * 64 + L);
            #pragma unroll
            for (int nt = 0; nt < 4; ++nt)
                acc[nt] = __builtin_amdgcn_mfma_f32_16x16x32_bf16(a, pg[(size_t)nt * 64], acc[nt], 0, 0, 0);
        }
        #pragma unroll
        for (int nt = 0; nt < 4; ++nt) {
            int n = w * 64 + nt * 16 + (L & 15);
            float bv = Bgh[n];
            #pragma unroll
            for (int reg = 0; reg < 4; ++reg) {
                int tl = (L >> 4) * 4 + reg;
                gm[(size_t)(tl * B_ + b) * H_ + n] = f2b(__expf(-fmaxf(acc[nt][reg] + bv, 0.f)));
            }
        }
    }
}

// ===========================================================================
// scan block (R8): R6 pair-split structure with PER-WAVE flag protocol.
// Producer wave w's exports are exactly what partner wave w (c-tiles) and
// partner wave w^8 (z-tiles) consume. Each wave: export (relaxed) -> lane-0
// RELEASE flag store (compiler emits per-wave vmcnt drain, overlapped across
// waves) -> scattered preact prefetch -> poll flagP[w], flagP[w^8] -> import
// -> update. Block barriers per step: 2 (Apbf/zl ready; end-of-step WAR).
// No block-wide store-ACK drains on the critical path.
// ===========================================================================
__device__ void scan_block(char* sm, int p, int hb, int base, const bfu* __restrict__ pre,
                           const short* __restrict__ PUc, const unsigned char* __restrict__ PU8,
                           float* __restrict__ hws,
                           float* __restrict__ zx, float* __restrict__ cx,
                           u32* __restrict__ flags)
{
    char*  Abf8 = sm;                        // 8 KB fp8 A-fragments [16 kt][64][8] (full K)
    short* Apbf = (short*)(sm + 8192);       // 8 KB bf16 (A*r)-fragments, own K-half
    float* zl   = (float*)(sm + 16384);      // 16 KB f32 col-major [256 cols][16 rows]: own z
    const bfu* pz = pre;
    const bfu* pr = pre + SLOTS;
    const bfu* pc = pre + 2 * SLOTS;
    const bfu* gm = pre + 3 * SLOTS;
    const int tid = threadIdx.x, L = tid & 63, w = tid >> 6;
    const int b0 = p * 16;
    const i64* PU8q = (const i64*)PU8;
    const s16x8* PUcf = (const s16x8*)PUc;
    const float INV = 4.8828125e-4f;        // 1/2048

    int nn[2], ktq[2], lsh[2], j2;
    #pragma unroll
    for (int nt = 0; nt < 2; ++nt) {
        nn[nt] = w * 32 + nt * 16 + (L & 15);
        ktq[nt] = nn[nt] >> 5;
        lsh[nt] = ((nn[nt] >> 3) & 3) << 4;
    }
    j2 = nn[0] & 7;
    const int row0 = (L >> 4) * 4;
    const int ph = w >> 3;                   // half that this wave's nn cols live in
    const bool isR = (ph == hb);             // r/build wave group
    int lc[2];
    #pragma unroll
    for (int nt = 0; nt < 2; ++nt) lc[nt] = nn[nt] & 255;
    int pa_col[2];
    #pragma unroll
    for (int nt = 0; nt < 2; ++nt) pa_col[nt] = hb * 256 + lc[nt];
    const int tbase = (isR ? 512 : 0) + hb * 16 + (w & 7) * 2;

    float* zxO0 = zx + (size_t)(p * 2 + hb) * 2 * 4096;
    float* cxO0 = cx + (size_t)(p * 2 + hb) * 2 * 8192;
    float* zxP0 = zx + (size_t)(p * 2 + (1 - hb)) * 2 * 4096;
    float* cxP0 = cx + (size_t)(p * 2 + (1 - hb)) * 2 * 8192;
    u32* flagO = flags + (size_t)(p * 2 + hb) * 32;
    u32* flagP = flags + (size_t)(p * 2 + (1 - hb)) * 32;

    float A32[2][4];
    #pragma unroll
    for (int nt = 0; nt < 2; ++nt)
        #pragma unroll
        for (int reg = 0; reg < 4; ++reg) {
            int row = row0 + reg;
            float h = hws[(size_t)(b0 + row) * H_ + nn[nt]];
            float gv = b2f(gm[(size_t)(b0 + row) * H_ + nn[nt]]);   // tl = 0
            float A = gv * h;
            A32[nt][reg] = A;
            Abf8[(ktq[nt] * 64 + (row | lsh[nt])) * 8 + j2] = f2e4m3(A * 64.f);
        }
    __syncthreads();

    // phase-A pre-activations for tl=0 (later steps prefetched in the window)
    float lpa[2][4];       // lpr (isR group) or lpz (z group), at pa_col
    {
        const bfu* src = isR ? pr : pz;
        #pragma unroll
        for (int nt = 0; nt < 2; ++nt)
            #pragma unroll
            for (int reg = 0; reg < 4; ++reg)
                lpa[nt][reg] = b2f(src[(size_t)(0 * B_ + b0 + row0 + reg) * H_ + pa_col[nt]]);
    }

    for (int tl = 0; tl < CH; ++tl) {
        const int S = base + tl;
        const int par = S & 1;
        u64* zxOq = (u64*)(zxO0 + par * 4096);
        u64* cxOq = (u64*)(cxO0 + par * 8192);
        const u64* zxPq = (const u64*)(zxP0 + par * 4096);
        const u64* cxPq = (const u64*)(cxP0 + par * 8192);
        const int tln = (tl + 1 < CH) ? tl + 1 : tl;
        const u32 need = (u32)(S + 1);

        // ---- phase A: fp8 GEMM, 2 tiles/wave (z for z-group, r for isR) ----
        f32x4 a0 = (f32x4)0.f, a1 = (f32x4)0.f;
        #pragma unroll 4
        for (int kt = 0; kt < 16; ++kt) {
            i64 a8 = *(const i64*)&Abf8[(kt * 64 + L) * 8];
            i64 w0 = PU8q[((size_t)(kt * 32 + tbase)) * 64 + L];
            i64 w1 = PU8q[((size_t)(kt * 32 + tbase + 1)) * 64 + L];
            a0 = __builtin_amdgcn_mfma_f32_16x16x32_fp8_fp8(a8, w0, a0, 0, 0, 0);
            a1 = __builtin_amdgcn_mfma_f32_16x16x32_fp8_fp8(a8, w1, a1, 0, 0, 0);
        }
        if (isR) {
            // r in registers -> fold the (A*r) build directly into phase A
            #pragma unroll
            for (int reg = 0; reg < 4; ++reg) {
                float rg0 = sigf(a0[reg] * INV + lpa[0][reg]);
                float rg1 = sigf(a1[reg] * INV + lpa[1][reg]);
                int m = row0 + reg;
                Apbf[((lc[0] >> 5) * 64 + (m | lsh[0])) * 8 + j2] = (short)f2b(A32[0][reg] * rg0);
                Apbf[((lc[1] >> 5) * 64 + (m | lsh[1])) * 8 + j2] = (short)f2b(A32[1][reg] * rg1);
            }
        } else {
            // z -> zl LDS (col-major) + export (col-major, coalesced, relaxed)
            f32x4 zq0, zq1;
            #pragma unroll
            for (int reg = 0; reg < 4; ++reg) {
                zq0[reg] = sigf(a0[reg] * INV + lpa[0][reg]);
                zq1[reg] = sigf(a1[reg] * INV + lpa[1][reg]);
            }
            *(f32x4*)&zl[lc[0] * 16 + row0] = zq0;
            *(f32x4*)&zl[lc[1] * 16 + row0] = zq1;
            int i0 = (lc[0] * 16 + row0) >> 1, i1 = (lc[1] * 16 + row0) >> 1;
            __hip_atomic_store(&zxOq[i0],     pk2(zq0[0], zq0[1]), __ATOMIC_RELAXED, __HIP_MEMORY_SCOPE_AGENT);
            __hip_atomic_store(&zxOq[i0 + 1], pk2(zq0[2], zq0[3]), __ATOMIC_RELAXED, __HIP_MEMORY_SCOPE_AGENT);
            __hip_atomic_store(&zxOq[i1],     pk2(zq1[0], zq1[1]), __ATOMIC_RELAXED, __HIP_MEMORY_SCOPE_AGENT);
            __hip_atomic_store(&zxOq[i1 + 1], pk2(zq1[2], zq1[3]), __ATOMIC_RELAXED, __HIP_MEMORY_SCOPE_AGENT);
        }
        __syncthreads();   // (1) Apbf + zl ready for the c GEMM / update

        // ---- c bf16 GEMM: all cols, own K-half ----
        f32x4 ac[2];
        ac[0] = (f32x4)0.f; ac[1] = (f32x4)0.f;
        #pragma unroll 4
        for (int kk = 0; kk < 8; ++kk) {
            s16x8 a = *(const s16x8*)&Apbf[(kk * 64 + L) * 8];
            const s16x8* c8 = PUcf + ((size_t)((hb * 8 + kk) * 32 + w * 2) * 64 + L);
            s16x8 bc0 = c8[0], bc1 = c8[64];
            ac[0] = __builtin_amdgcn_mfma_f32_16x16x32_bf16(a, bc0, ac[0], 0, 0, 0);
            ac[1] = __builtin_amdgcn_mfma_f32_16x16x32_bf16(a, bc1, ac[1], 0, 0, 0);
        }
        // col-major export of c-partials (2 u64 per tile, coalesced, relaxed)
        #pragma unroll
        for (int nt = 0; nt < 2; ++nt) {
            int ix = (nn[nt] * 16 + row0) >> 1;
            __hip_atomic_store(&cxOq[ix],     pk2(ac[nt][0], ac[nt][1]), __ATOMIC_RELAXED, __HIP_MEMORY_SCOPE_AGENT);
            __hip_atomic_store(&cxOq[ix + 1], pk2(ac[nt][2], ac[nt][3]), __ATOMIC_RELAXED, __HIP_MEMORY_SCOPE_AGENT);
        }
        // per-wave RELEASE flag: orders this wave's z + c exports (vmcnt drain
        // is per-wave and overlaps across the block's 16 waves)
        if (L == 0)
            __hip_atomic_store(&flagO[w], need, __ATOMIC_RELEASE, __HIP_MEMORY_SCOPE_AGENT);

        // ---- prefetch update operands (this tl) + phase-A preacts (next tl);
        //      latency hides under the partner round-trip ----
        float lpcv[2][4], lgmv[2][4];
        #pragma unroll
        for (int nt = 0; nt < 2; ++nt)
            #pragma unroll
            for (int reg = 0; reg < 4; ++reg) {
                int row = b0 + row0 + reg;
                lpcv[nt][reg] = b2f(pc[(size_t)(tl * B_ + row) * H_ + nn[nt]]);
                lgmv[nt][reg] = b2f(gm[(size_t)(tln * B_ + row) * H_ + nn[nt]]);
            }
        {
            const bfu* src = isR ? pr : pz;
            #pragma unroll
            for (int nt = 0; nt < 2; ++nt)
                #pragma unroll
                for (int reg = 0; reg < 4; ++reg)
                    lpa[nt][reg] = b2f(src[(size_t)(tln * B_ + b0 + row0 + reg) * H_ + pa_col[nt]]);
        }

        // ---- per-wave poll: partner wave w (c) and w^8 (z) ----
        while (__hip_atomic_load(&flagP[w], __ATOMIC_RELAXED, __HIP_MEMORY_SCOPE_AGENT) < need ||
               __hip_atomic_load(&flagP[w ^ 8], __ATOMIC_RELAXED, __HIP_MEMORY_SCOPE_AGENT) < need)
            __builtin_amdgcn_s_sleep(1);

        // ---- import partner data direct to registers ----
        u64 ci0[2], ci1[2], zi0[2], zi1[2];
        #pragma unroll
        for (int nt = 0; nt < 2; ++nt) {
            int ix = (nn[nt] * 16 + row0) >> 1;
            ci0[nt] = __hip_atomic_load(&cxPq[ix],     __ATOMIC_RELAXED, __HIP_MEMORY_SCOPE_AGENT);
            ci1[nt] = __hip_atomic_load(&cxPq[ix + 1], __ATOMIC_RELAXED, __HIP_MEMORY_SCOPE_AGENT);
        }
        if (!isR) {
            #pragma unroll
            for (int nt = 0; nt < 2; ++nt) {
                int iz = (lc[nt] * 16 + row0) >> 1;
                zi0[nt] = __hip_atomic_load(&zxPq[iz],     __ATOMIC_RELAXED, __HIP_MEMORY_SCOPE_AGENT);
                zi1[nt] = __hip_atomic_load(&zxPq[iz + 1], __ATOMIC_RELAXED, __HIP_MEMORY_SCOPE_AGENT);
            }
        }

        // ---- state update ----
        #pragma unroll
        for (int nt = 0; nt < 2; ++nt) {
            float cpe[4] = { lo2(ci0[nt]), hi2(ci0[nt]), lo2(ci1[nt]), hi2(ci1[nt]) };
            float zg[4];
            if (isR) {
                f32x4 zv = *(const f32x4*)&zl[lc[nt] * 16 + row0];
                zg[0] = zv[0]; zg[1] = zv[1]; zg[2] = zv[2]; zg[3] = zv[3];
            } else {
                zg[0] = lo2(zi0[nt]); zg[1] = hi2(zi0[nt]);
                zg[2] = lo2(zi1[nt]); zg[3] = hi2(zi1[nt]);
            }
            #pragma unroll
            for (int reg = 0; reg < 4; ++reg) {
                int m = row0 + reg;
                float cc = tanhfast(ac[nt][reg] + cpe[reg] + lpcv[nt][reg]);
                float hn = (1.f - zg[reg]) * A32[nt][reg] + zg[reg] * cc;
                if (tl < CH - 1) {
                    float An = lgmv[nt][reg] * hn;
                    A32[nt][reg] = An;
                    Abf8[(ktq[nt] * 64 + (m | lsh[nt])) * 8 + j2] = f2e4m3(An * 64.f);
                } else if (isR) {
                    hws[(size_t)(b0 + m) * H_ + nn[nt]] = hn;
                }
            }
        }
        __syncthreads();   // (2) Abf8/zl/Apbf safe to overwrite next step
    }
}

// ===========================================================================
// fused launch: blocks 0-31 scan chunk c-1 (16 pairs x 2 halves);
// blocks 32-159 (2x512-thr units) compute pre-activations for chunk c.
// ===========================================================================
__global__ __launch_bounds__(1024) void k_fused(int c,
    const float* __restrict__ x, const float* __restrict__ dl,
    const float* __restrict__ mk, const float* __restrict__ xf,
    const float* __restrict__ bz, const float* __restrict__ br, const float* __restrict__ bc,
    const float* __restrict__ Bgh,
    const float* __restrict__ Wgx, const float* __restrict__ Bgx,
    const short* __restrict__ PW, const short* __restrict__ PG,
    const short* __restrict__ PUc, const unsigned char* __restrict__ PU8,
    bfu* __restrict__ buf0, bfu* __restrict__ buf1, float* __restrict__ hws,
    float* __restrict__ zx, float* __restrict__ cx, u32* __restrict__ flags)
{
    __shared__ char sm[32768];
    if (blockIdx.x < 32) {
        if (c == 0) return;
        const bfu* pre = (c & 1) ? buf0 : buf1;    // chunk c-1 lives in buf[(c-1)&1]
        int p = blockIdx.x & 15, hb = blockIdx.x >> 4;
        scan_block(sm, p, hb, (c - 1) * CH, pre, PUc, PU8, hws, zx, cx, flags);
    } else {
        if (c >= NCH) return;
        int unit = ((int)blockIdx.x - 32) * 2 + (threadIdx.x >> 9);
        if (unit >= B_) return;
        bfu* dst = (c & 1) ? buf1 : buf0;           // chunk c -> buf[c&1]
        k1_unit(sm + (threadIdx.x >> 9) * 12288, unit, c * CH,
                x, dl, mk, xf, bz, br, bc, Bgh, Wgx, Bgx, PW, PG,
                dst, dst + SLOTS, dst + 2 * SLOTS, dst + 3 * SLOTS);
    }
}

// ===========================================================================
// k3: BatchNorm(eval) + decoder GEMV + log_softmax.
// ===========================================================================
__global__ __launch_bounds__(128) void k3_out(
    const float* __restrict__ hws,
    const float* __restrict__ dW, const float* __restrict__ db,
    const float* __restrict__ bng, const float* __restrict__ bnb,
    float* __restrict__ out)
{
    __shared__ float hb[H_];
    __shared__ float red[O_];
    const int tid = threadIdx.x;
    const int b = blockIdx.x;
    const float s = 0.9999950000374997f;   // 1/sqrt(1 + 1e-5)
    for (int k = tid; k < H_; k += O_) {
        float v = hws[(size_t)b * H_ + k] * s * bng[k] + bnb[k];
        hb[k] = v;
        out[B_ * O_ + (size_t)b * H_ + k] = v;
    }
    __syncthreads();
    float acc = db[tid];
    #pragma unroll 4
    for (int k = 0; k < H_; ++k) acc += hb[k] * dW[(size_t)k * O_ + tid];
    red[tid] = acc;
    __syncthreads();
    for (int sh = 64; sh > 0; sh >>= 1) {
        if (tid < sh) red[tid] = fmaxf(red[tid], red[tid + sh]);
        __syncthreads();
    }
    float mx = red[0];
    __syncthreads();
    red[tid] = __expf(acc - mx);
    __syncthreads();
    for (int sh = 64; sh > 0; sh >>= 1) {
        if (tid < sh) red[tid] += red[tid + sh];
        __syncthreads();
    }
    float lse = __logf(red[0]) + mx;
    out[(size_t)b * O_ + tid] = acc - lse;
}

extern "C" void kernel_launch(void* const* d_in, const int* in_sizes, int n_in,
                              void* d_out, int out_size, void* d_ws, size_t ws_size,
                              hipStream_t stream)
{
    (void)in_sizes; (void)n_in; (void)out_size; (void)ws_size;
    const float* x   = (const float*)d_in[0];
    const float* dl  = (const float*)d_in[1];
    const float* m   = (const float*)d_in[2];
    const float* xf  = (const float*)d_in[3];
    const float* Wr  = (const float*)d_in[4];
    const float* Ur  = (const float*)d_in[5];
    const float* Vr  = (const float*)d_in[6];
    const float* br  = (const float*)d_in[7];
    const float* Wz  = (const float*)d_in[8];
    const float* Uz  = (const float*)d_in[9];
    const float* Vz  = (const float*)d_in[10];
    const float* bz  = (const float*)d_in[11];
    const float* Wc  = (const float*)d_in[12];
    const float* Uc  = (const float*)d_in[13];
    const float* Vc  = (const float*)d_in[14];
    const float* bc  = (const float*)d_in[15];
    const float* Wgx = (const float*)d_in[16];
    const float* Bgx = (const float*)d_in[17];
    const float* Wgh = (const float*)d_in[18];
    const float* Bgh = (const float*)d_in[19];
    const float* dW  = (const float*)d_in[20];
    const float* db  = (const float*)d_in[21];
    const float* bng = (const float*)d_in[22];
    const float* bnb = (const float*)d_in[23];

    char* p = (char*)d_ws;
    short* PW = (short*)p;              p += (size_t)3 * 256 * 64 * 8 * 2;   // 768 KB
    short* PG = (short*)p;              p += (size_t)128 * 64 * 8 * 2;       // 128 KB
    short* PUc = (short*)p;             p += (size_t)512 * 64 * 8 * 2;       // 512 KB
    unsigned char* PU8 = (unsigned char*)p; p += (size_t)1024 * 64 * 8;      // 512 KB
    bfu* buf0 = (bfu*)p;                p += 4 * SLOTS * 2;                  // 16 MB
    bfu* buf1 = (bfu*)p;                p += 4 * SLOTS * 2;                  // 16 MB
    float* hws = (float*)p;             p += (size_t)B_ * H_ * 4;            // 512 KB
    float* zx  = (float*)p;             p += (size_t)16 * 2 * 2 * 4096 * 4;  // 1 MB
    float* cx  = (float*)p;             p += (size_t)16 * 2 * 2 * 8192 * 4;  // 2 MB
    u32* flags = (u32*)p;                                                    // 4 KB

    hipMemsetAsync(hws, 0, (size_t)B_ * H_ * sizeof(float), stream);
    hipMemsetAsync(flags, 0, (size_t)32 * 32 * sizeof(u32), stream);
    k_pack<<<dim3(608), dim3(256), 0, stream>>>(Wz, Wr, Wc, Vz, Vr, Vc, Wgh,
                                                Uz, Ur, Uc, PW, PG, PUc, PU8);
    for (int c = 0; c <= NCH; ++c) {
        k_fused<<<dim3(160), dim3(1024), 0, stream>>>(c,
            x, dl, m, xf, bz, br, bc, Bgh, Wgx, Bgx,
            PW, PG, PUc, PU8, buf0, buf1, hws, zx, cx, flags);
    }
    k3_out<<<dim3(B_), dim3(O_), 0, stream>>>(hws, dW, db, bng, bnb, (float*)d_out);
}

// Round 9
// 3192.153 us; speedup vs baseline: 1.6883x; 1.6883x over previous
//
#include <hip/hip_runtime.h>
#include <stdint.h>

typedef float  f32x4 __attribute__((ext_vector_type(4)));
typedef short  s16x8 __attribute__((ext_vector_type(8)));
typedef unsigned int u32;
typedef unsigned long long u64;
typedef unsigned short bfu;
typedef long long i64;

#define B_ 256
#define T_ 256
#define I_ 128
#define H_ 512
#define O_ 128
#define CH 16
#define NCH (T_ / CH)
#define SLOTS ((size_t)CH * B_ * H_)   // elems per bf16 pre-array

__device__ __forceinline__ bfu f2b(float f) {
    u32 u = __float_as_uint(f);
    u += 0x7fffu + ((u >> 16) & 1u);
    return (bfu)(u >> 16);
}
__device__ __forceinline__ float b2f(bfu b) { return __uint_as_float(((u32)b) << 16); }
__device__ __forceinline__ float sigf(float x) { return 1.f / (1.f + __expf(-x)); }
__device__ __forceinline__ float tanhfast(float x) { return 1.f - 2.f / (__expf(2.f * x) + 1.f); }
__device__ __forceinline__ u64 pk2(float a, float b) {
    return (u64)__float_as_uint(a) | ((u64)__float_as_uint(b) << 32);
}
__device__ __forceinline__ float lo2(u64 v) { return __uint_as_float((u32)v); }
__device__ __forceinline__ float hi2(u64 v) { return __uint_as_float((u32)(v >> 32)); }

// software float -> OCP e4m3fn, RNE, saturating
__device__ __forceinline__ unsigned char f2e4m3(float f) {
    u32 u = __float_as_uint(f);
    u32 s = (u >> 24) & 0x80u;
    u &= 0x7fffffffu;
    if (u >= 0x43e00000u) return (unsigned char)(s | 0x7eu);    // >= 448 -> sat
    if (u < 0x3c800000u) {                                       // < 2^-6 -> subnormal
        int m = __float2int_rn(__uint_as_float(u) * 512.f);
        if (m >= 8) return (unsigned char)(s | 0x08u);
        return (unsigned char)(s | (u32)m);
    }
    u += 0x7ffffu + ((u >> 20) & 1u);                            // RNE at bit 20
    u32 e8 = ((u >> 23) & 0xffu) - 120u;                         // bias 127 -> 7
    return (unsigned char)(s | (e8 << 3) | ((u >> 20) & 7u));
}

// hardware fp8 conversion where available (gfx950: OCP e4m3, RNE — same
// rounding as the software path; inputs here are bounded |x| <= 64 < 448)
#if defined(__has_builtin)
#if __has_builtin(__builtin_amdgcn_cvt_pk_fp8_f32)
#define HW_FP8 1
#endif
#endif
#ifdef HW_FP8
__device__ __forceinline__ unsigned char f2e4m3_fast(float f) {
    return (unsigned char)(__builtin_amdgcn_cvt_pk_fp8_f32(f, f, 0, 0) & 0xffu);
}
#else
#define f2e4m3_fast f2e4m3
#endif

// ===========================================================================
// k_pack: weights -> MFMA B-fragment order.
// frag 16x16x32: lane L holds B[k = kt*32 + (L>>4)*8 + j][n = nt*16 + (L&15)].
// PW bf16 (W|V per gate), PG bf16 (Wgh), PUc bf16 (Uc), PU8 fp8 (Uz,Ur x32).
// ===========================================================================
__global__ __launch_bounds__(256) void k_pack(
    const float* __restrict__ Wz, const float* __restrict__ Wr, const float* __restrict__ Wc,
    const float* __restrict__ Vz, const float* __restrict__ Vr, const float* __restrict__ Vc,
    const float* __restrict__ Wgh,
    const float* __restrict__ Uz, const float* __restrict__ Ur, const float* __restrict__ Uc,
    short* __restrict__ PW, short* __restrict__ PG, short* __restrict__ PUc,
    unsigned char* __restrict__ PU8)
{
    int wv = blockIdx.x * 4 + (threadIdx.x >> 6);
    int L = threadIdx.x & 63;
    if (wv >= 2432) return;
    int koff = (L >> 4) << 3;
    int ncol;
    if (wv < 768) {                       // PW: gate x (kt<4:W, kt>=4:V)
        int g = wv >> 8, rem = wv & 255;
        int kt = rem >> 5; ncol = (rem & 31) * 16 + (L & 15);
        const float* src = (kt < 4) ? (g == 0 ? Wz : g == 1 ? Wr : Wc)
                                    : (g == 0 ? Vz : g == 1 ? Vr : Vc);
        int kbase = (kt & 3) * 32 + koff;
        s16x8 v;
        #pragma unroll
        for (int j = 0; j < 8; ++j) v[j] = (short)f2b(src[(kbase + j) * H_ + ncol]);
        *(s16x8*)&PW[((size_t)(g * 256 + rem) * 64 + L) * 8] = v;
    } else if (wv < 896) {                // PG
        int rem = wv - 768;
        ncol = (rem & 31) * 16 + (L & 15);
        int kbase = (rem >> 5) * 32 + koff;
        s16x8 v;
        #pragma unroll
        for (int j = 0; j < 8; ++j) v[j] = (short)f2b(Wgh[(kbase + j) * H_ + ncol]);
        *(s16x8*)&PG[((size_t)rem * 64 + L) * 8] = v;
    } else if (wv < 1408) {               // PUc bf16
        int rem = wv - 896;               // kt*32+nt, kt 0..15
        ncol = (rem & 31) * 16 + (L & 15);
        int kbase = (rem >> 5) * 32 + koff;
        s16x8 v;
        #pragma unroll
        for (int j = 0; j < 8; ++j) v[j] = (short)f2b(Uc[(kbase + j) * H_ + ncol]);
        *(s16x8*)&PUc[((size_t)rem * 64 + L) * 8] = v;
    } else {                              // PU8: Uz, Ur scaled x32, e4m3
        int rem = wv - 1408;              // g*512 + kt*32 + nt
        int g = rem >> 9, r2 = rem & 511;
        ncol = (r2 & 31) * 16 + (L & 15);
        int kbase = (r2 >> 5) * 32 + koff;
        const float* src = (g == 0) ? Uz : Ur;
        unsigned char* d = PU8 + ((size_t)rem * 64 + L) * 8;
        #pragma unroll
        for (int j = 0; j < 8; ++j) d[j] = f2e4m3(src[(kbase + j) * H_ + ncol] * 32.f);
    }
}

// ===========================================================================
// k1 unit: input-side projections for one batch row b, 16 timesteps.
// 512 threads (8 waves x 64 cols). bf16 outputs, layout [tl][b][H].
// ===========================================================================
__device__ void k1_unit(char* sm, int b, int t0,
    const float* __restrict__ x, const float* __restrict__ dl,
    const float* __restrict__ mk, const float* __restrict__ xf,
    const float* __restrict__ bz, const float* __restrict__ br, const float* __restrict__ bc,
    const float* __restrict__ Bgh,
    const float* __restrict__ Wgx, const float* __restrict__ Bgx,
    const short* __restrict__ PW, const short* __restrict__ PG,
    bfu* __restrict__ pz, bfu* __restrict__ pr, bfu* __restrict__ pc, bfu* __restrict__ gm)
{
    short* Abuf = (short*)sm;             // 12 KB: [kt 0..11][lane][8]
    const int t = threadIdx.x & 511;
    const int L = t & 63, w = t >> 6;

    for (int cc = t; cc < 12 * 64; cc += 512) {
        int Ls = cc & 63, kt = cc >> 6;
        int tl = Ls & 15, q = Ls >> 4;
        int gbase = (b * T_ + t0 + tl) * I_;
        s16x8 v;
        if (kt < 4) {
            int kb = kt * 32 + q * 8;
            f32x4 m0 = *(const f32x4*)&mk[gbase + kb], m1 = *(const f32x4*)&mk[gbase + kb + 4];
            f32x4 d0 = *(const f32x4*)&dl[gbase + kb], d1 = *(const f32x4*)&dl[gbase + kb + 4];
            f32x4 f0 = *(const f32x4*)&xf[gbase + kb], f1 = *(const f32x4*)&xf[gbase + kb + 4];
            f32x4 x0 = *(const f32x4*)&x[gbase + kb],  x1 = *(const f32x4*)&x[gbase + kb + 4];
            #pragma unroll
            for (int j = 0; j < 8; ++j) {
                int k = kb + j;
                float mv = (j < 4) ? m0[j] : m1[j - 4];
                float dv = (j < 4) ? d0[j] : d1[j - 4];
                float fv = (j < 4) ? f0[j] : f1[j - 4];
                float xv = (j < 4) ? x0[j] : x1[j - 4];
                float dx = dv * Wgx[k] + Bgx[k];
                float xr = dx * fv + (1.f - dx) * 0.001f;
                v[j] = (short)f2b((mv > 0.5f) ? xr : xv);
            }
        } else if (kt < 8) {
            int kb = (kt - 4) * 32 + q * 8;
            f32x4 m0 = *(const f32x4*)&mk[gbase + kb], m1 = *(const f32x4*)&mk[gbase + kb + 4];
            #pragma unroll
            for (int j = 0; j < 8; ++j) v[j] = (short)f2b(1.f - ((j < 4) ? m0[j] : m1[j - 4]));
        } else {
            int kb = (kt - 8) * 32 + q * 8;
            f32x4 m0 = *(const f32x4*)&mk[gbase + kb], m1 = *(const f32x4*)&mk[gbase + kb + 4];
            #pragma unroll
            for (int j = 0; j < 8; ++j) v[j] = (short)f2b((j < 4) ? m0[j] : m1[j - 4]);
        }
        *(s16x8*)&Abuf[(size_t)cc * 8] = v;
    }
    __syncthreads();

    const s16x8* PWf = (const s16x8*)PW;
    const s16x8* PGf = (const s16x8*)PG;

    for (int g = 0; g < 3; ++g) {
        f32x4 acc[4];
        #pragma unroll
        for (int nt = 0; nt < 4; ++nt) acc[nt] = (f32x4)0.f;
        for (int kt = 0; kt < 8; ++kt) {
            s16x8 a = *(const s16x8*)&Abuf[(kt * 64 + L) * 8];
            const s16x8* pw = PWf + ((size_t)(g * 256 + kt * 32 + w * 4) * 64 + L);
            #pragma unroll
            for (int nt = 0; nt < 4; ++nt)
                acc[nt] = __builtin_amdgcn_mfma_f32_16x16x32_bf16(a, pw[(size_t)nt * 64], acc[nt], 0, 0, 0);
        }
        const float* bias = (g == 0) ? bz : (g == 1) ? br : bc;
        bfu* dst = (g == 0) ? pz : (g == 1) ? pr : pc;
        #pragma unroll
        for (int nt = 0; nt < 4; ++nt) {
            int n = w * 64 + nt * 16 + (L & 15);
            float bv = bias[n];
            #pragma unroll
            for (int reg = 0; reg < 4; ++reg) {
                int tl = (L >> 4) * 4 + reg;
                dst[(size_t)(tl * B_ + b) * H_ + n] = f2b(acc[nt][reg] + bv);
            }
        }
    }
    {
        f32x4 acc[4];
        #pragma unroll
        for (int nt = 0; nt < 4; ++nt) acc[nt] = (f32x4)0.f;
        for (int kk = 0; kk < 4; ++kk) {
            s16x8 a = *(const s16x8*)&Abuf[((8 + kk) * 64 + L) * 8];
            const s16x8* pg = PGf + ((size_t)(kk * 32 + w * 4) * 64 + L);
            #pragma unroll
            for (int nt = 0; nt < 4; ++nt)
                acc[nt] = __builtin_amdgcn_mfma_f32_16x16x32_bf16(a, pg[(size_t)nt * 64], acc[nt], 0, 0, 0);
        }
        #pragma unroll
        for (int nt = 0; nt < 4; ++nt) {
            int n = w * 64 + nt * 16 + (L & 15);
            float bv = Bgh[n];
            #pragma unroll
            for (int reg = 0; reg < 4; ++reg) {
                int tl = (L >> 4) * 4 + reg;
                gm[(size_t)(tl * B_ + b) * H_ + n] = f2b(__expf(-fmaxf(acc[nt][reg] + bv, 0.f)));
            }
        }
    }
}

// ===========================================================================
// scan block (R9 = R6 protocol + VALU diet): pair p rows [16p,16p+16); half
// hb owns z/r cols [hb*256,+256) and c-GEMM K-rows [hb*256,+256).
// VALU reductions vs R6: (a) hardware fp8 convert (cvt_pk_fp8) for the 8
// Abf8 state writes/thread/step, (b) all loop-invariant addressing hoisted
// (preact base pointers, weight pointers, exchange indices) so in-loop
// addresses are base + uniform offset + small imm.
// Sync protocol identical to R6: 4 block barriers, tid0 flag + poll.
// ===========================================================================
__device__ void scan_block(char* sm, int p, int hb, int base, const bfu* __restrict__ pre,
                           const short* __restrict__ PUc, const unsigned char* __restrict__ PU8,
                           float* __restrict__ hws,
                           float* __restrict__ zx, float* __restrict__ cx,
                           u32* __restrict__ flags)
{
    char*  Abf8 = sm;                        // 8 KB fp8 A-fragments [16 kt][64][8] (full K)
    short* Apbf = (short*)(sm + 8192);       // 8 KB bf16 (A*r)-fragments, own K-half
    float* zl   = (float*)(sm + 16384);      // 16 KB f32 col-major [256 cols][16 rows]: own z
    const bfu* pz = pre;
    const bfu* pr = pre + SLOTS;
    const bfu* pc = pre + 2 * SLOTS;
    const bfu* gm = pre + 3 * SLOTS;
    const int tid = threadIdx.x, L = tid & 63, w = tid >> 6;
    const int b0 = p * 16;
    const i64* PU8q = (const i64*)PU8;
    const s16x8* PUcf = (const s16x8*)PUc;
    const float INV = 4.8828125e-4f;        // 1/2048
    const int BH = B_ * H_;                  // per-timestep preact stride

    int nn[2], ktq[2], lsh[2], j2;
    #pragma unroll
    for (int nt = 0; nt < 2; ++nt) {
        nn[nt] = w * 32 + nt * 16 + (L & 15);
        ktq[nt] = nn[nt] >> 5;
        lsh[nt] = ((nn[nt] >> 3) & 3) << 4;
    }
    j2 = nn[0] & 7;
    const int row0 = (L >> 4) * 4;
    const int ph = w >> 3;                   // half that this wave's nn cols live in
    const bool isR = (ph == hb);             // r/build wave group
    int lc[2], pa_col[2];
    #pragma unroll
    for (int nt = 0; nt < 2; ++nt) {
        lc[nt] = nn[nt] & 255;
        pa_col[nt] = hb * 256 + lc[nt];
    }
    const int tbase = (isR ? 512 : 0) + hb * 16 + (w & 7) * 2;

    // ---- hoisted loop-invariant bases ----
    const i64*   wp  = PU8q + (size_t)tbase * 64 + L;                    // phase-A weights
    const s16x8* cwp = PUcf + ((size_t)(hb * 8) * 32 + w * 2) * 64 + L;  // c weights
    const bfu* srcA = isR ? pr : pz;
    const bfu* paB[2]; const bfu* pcB[2]; const bfu* gmB[2];
    #pragma unroll
    for (int nt = 0; nt < 2; ++nt) {
        paB[nt] = srcA + (size_t)(b0 + row0) * H_ + pa_col[nt];
        pcB[nt] = pc   + (size_t)(b0 + row0) * H_ + nn[nt];
        gmB[nt] = gm   + (size_t)(b0 + row0) * H_ + nn[nt];
    }
    int ixc[2], izc[2];
    #pragma unroll
    for (int nt = 0; nt < 2; ++nt) {
        ixc[nt] = (nn[nt] * 16 + row0) >> 1;
        izc[nt] = (lc[nt] * 16 + row0) >> 1;
    }

    float* zxO0 = zx + (size_t)(p * 2 + hb) * 2 * 4096;
    float* cxO0 = cx + (size_t)(p * 2 + hb) * 2 * 8192;
    float* zxP0 = zx + (size_t)(p * 2 + (1 - hb)) * 2 * 4096;
    float* cxP0 = cx + (size_t)(p * 2 + (1 - hb)) * 2 * 8192;
    u32* flagO = flags + (size_t)(p * 2 + hb) * 32;
    u32* flagP = flags + (size_t)(p * 2 + (1 - hb)) * 32;

    float A32[2][4];
    #pragma unroll
    for (int nt = 0; nt < 2; ++nt)
        #pragma unroll
        for (int reg = 0; reg < 4; ++reg) {
            int row = row0 + reg;
            float h = hws[(size_t)(b0 + row) * H_ + nn[nt]];
            float gv = b2f(gmB[nt][reg * H_]);                     // gm(tl=0)
            float A = gv * h;
            A32[nt][reg] = A;
            Abf8[(ktq[nt] * 64 + (row | lsh[nt])) * 8 + j2] = f2e4m3_fast(A * 64.f);
        }
    __syncthreads();

    // phase-A pre-activations for tl=0 (later steps prefetched in the window)
    float lpa[2][4];
    #pragma unroll
    for (int nt = 0; nt < 2; ++nt)
        #pragma unroll
        for (int reg = 0; reg < 4; ++reg)
            lpa[nt][reg] = b2f(paB[nt][reg * H_]);

    for (int tl = 0; tl < CH; ++tl) {
        const int S = base + tl;
        const int par = S & 1;
        u64* zxOq = (u64*)(par ? zxO0 + 4096 : zxO0);
        u64* cxOq = (u64*)(par ? cxO0 + 8192 : cxO0);
        const u64* zxPq = (const u64*)(par ? zxP0 + 4096 : zxP0);
        const u64* cxPq = (const u64*)(par ? cxP0 + 8192 : cxP0);
        const int tln = (tl + 1 < CH) ? tl + 1 : tl;
        const int off  = tl * BH;            // uniform (SALU) offsets
        const int offn = tln * BH;

        // ---- phase A: fp8 GEMM, 2 tiles/wave (z for z-group, r for isR) ----
        f32x4 a0 = (f32x4)0.f, a1 = (f32x4)0.f;
        #pragma unroll 4
        for (int kt = 0; kt < 16; ++kt) {
            i64 a8 = *(const i64*)&Abf8[(kt * 64 + L) * 8];
            i64 w0 = wp[(size_t)kt * 2048];
            i64 w1 = wp[(size_t)kt * 2048 + 64];
            a0 = __builtin_amdgcn_mfma_f32_16x16x32_fp8_fp8(a8, w0, a0, 0, 0, 0);
            a1 = __builtin_amdgcn_mfma_f32_16x16x32_fp8_fp8(a8, w1, a1, 0, 0, 0);
        }
        if (isR) {
            // r in registers -> fold the (A*r) build directly into phase A
            #pragma unroll
            for (int reg = 0; reg < 4; ++reg) {
                float rg0 = sigf(a0[reg] * INV + lpa[0][reg]);
                float rg1 = sigf(a1[reg] * INV + lpa[1][reg]);
                int m = row0 + reg;
                Apbf[((lc[0] >> 5) * 64 + (m | lsh[0])) * 8 + j2] = (short)f2b(A32[0][reg] * rg0);
                Apbf[((lc[1] >> 5) * 64 + (m | lsh[1])) * 8 + j2] = (short)f2b(A32[1][reg] * rg1);
            }
        } else {
            // z -> zl LDS (col-major) + export (col-major, coalesced)
            f32x4 zq0, zq1;
            #pragma unroll
            for (int reg = 0; reg < 4; ++reg) {
                zq0[reg] = sigf(a0[reg] * INV + lpa[0][reg]);
                zq1[reg] = sigf(a1[reg] * INV + lpa[1][reg]);
            }
            *(f32x4*)&zl[lc[0] * 16 + row0] = zq0;
            *(f32x4*)&zl[lc[1] * 16 + row0] = zq1;
            __hip_atomic_store(&zxOq[izc[0]],     pk2(zq0[0], zq0[1]), __ATOMIC_RELAXED, __HIP_MEMORY_SCOPE_AGENT);
            __hip_atomic_store(&zxOq[izc[0] + 1], pk2(zq0[2], zq0[3]), __ATOMIC_RELAXED, __HIP_MEMORY_SCOPE_AGENT);
            __hip_atomic_store(&zxOq[izc[1]],     pk2(zq1[0], zq1[1]), __ATOMIC_RELAXED, __HIP_MEMORY_SCOPE_AGENT);
            __hip_atomic_store(&zxOq[izc[1] + 1], pk2(zq1[2], zq1[3]), __ATOMIC_RELAXED, __HIP_MEMORY_SCOPE_AGENT);
        }
        __syncthreads();   // (1) Apbf + zl ready (z exports drained here too)

        // ---- c bf16 GEMM: all cols, own K-half ----
        f32x4 ac[2];
        ac[0] = (f32x4)0.f; ac[1] = (f32x4)0.f;
        #pragma unroll 4
        for (int kk = 0; kk < 8; ++kk) {
            s16x8 a = *(const s16x8*)&Apbf[(kk * 64 + L) * 8];
            s16x8 bc0 = cwp[(size_t)kk * 2048];
            s16x8 bc1 = cwp[(size_t)kk * 2048 + 64];
            ac[0] = __builtin_amdgcn_mfma_f32_16x16x32_bf16(a, bc0, ac[0], 0, 0, 0);
            ac[1] = __builtin_amdgcn_mfma_f32_16x16x32_bf16(a, bc1, ac[1], 0, 0, 0);
        }
        // col-major export of c-partials (2 u64 per tile, coalesced)
        #pragma unroll
        for (int nt = 0; nt < 2; ++nt) {
            __hip_atomic_store(&cxOq[ixc[nt]],     pk2(ac[nt][0], ac[nt][1]), __ATOMIC_RELAXED, __HIP_MEMORY_SCOPE_AGENT);
            __hip_atomic_store(&cxOq[ixc[nt] + 1], pk2(ac[nt][2], ac[nt][3]), __ATOMIC_RELAXED, __HIP_MEMORY_SCOPE_AGENT);
        }
        __syncthreads();   // (2) all waves' exports drained (vmcnt 0 before barrier)
        if (tid == 0)
            __hip_atomic_store(flagO, (u32)(S + 1), __ATOMIC_RELEASE, __HIP_MEMORY_SCOPE_AGENT);

        // ---- prefetch update operands (this tl) + phase-A preacts (next tl);
        //      latency hides under the partner round-trip ----
        float lpcv[2][4], lgmv[2][4];
        #pragma unroll
        for (int nt = 0; nt < 2; ++nt)
            #pragma unroll
            for (int reg = 0; reg < 4; ++reg) {
                lpcv[nt][reg] = b2f(pcB[nt][off + reg * H_]);
                lgmv[nt][reg] = b2f(gmB[nt][offn + reg * H_]);
                lpa[nt][reg]  = b2f(paB[nt][offn + reg * H_]);
            }

        if (tid == 0) {
            while (__hip_atomic_load(flagP, __ATOMIC_RELAXED, __HIP_MEMORY_SCOPE_AGENT) < (u32)(S + 1))
                __builtin_amdgcn_s_sleep(1);
        }
        __syncthreads();   // (3) partner data ready

        // ---- import partner data direct to registers + state update ----
        #pragma unroll
        for (int nt = 0; nt < 2; ++nt) {
            u64 c0 = __hip_atomic_load(&cxPq[ixc[nt]],     __ATOMIC_RELAXED, __HIP_MEMORY_SCOPE_AGENT);
            u64 c1 = __hip_atomic_load(&cxPq[ixc[nt] + 1], __ATOMIC_RELAXED, __HIP_MEMORY_SCOPE_AGENT);
            float cpe[4] = { lo2(c0), hi2(c0), lo2(c1), hi2(c1) };
            float zg[4];
            if (isR) {
                f32x4 zv = *(const f32x4*)&zl[lc[nt] * 16 + row0];
                zg[0] = zv[0]; zg[1] = zv[1]; zg[2] = zv[2]; zg[3] = zv[3];
            } else {
                u64 z0 = __hip_atomic_load(&zxPq[izc[nt]],     __ATOMIC_RELAXED, __HIP_MEMORY_SCOPE_AGENT);
                u64 z1 = __hip_atomic_load(&zxPq[izc[nt] + 1], __ATOMIC_RELAXED, __HIP_MEMORY_SCOPE_AGENT);
                zg[0] = lo2(z0); zg[1] = hi2(z0); zg[2] = lo2(z1); zg[3] = hi2(z1);
            }
            #pragma unroll
            for (int reg = 0; reg < 4; ++reg) {
                int m = row0 + reg;
                float cc = tanhfast(ac[nt][reg] + cpe[reg] + lpcv[nt][reg]);
                float hn = (1.f - zg[reg]) * A32[nt][reg] + zg[reg] * cc;
                if (tl < CH - 1) {
                    float An = lgmv[nt][reg] * hn;
                    A32[nt][reg] = An;
                    Abf8[(ktq[nt] * 64 + (m | lsh[nt])) * 8 + j2] = f2e4m3_fast(An * 64.f);
                } else if (isR) {
                    hws[(size_t)(b0 + m) * H_ + nn[nt]] = hn;
                }
            }
        }
        __syncthreads();   // (4) Abf8/zl/Apbf safe to overwrite next step
    }
}

// ===========================================================================
// fused launch: blocks 0-31 scan chunk c-1 (16 pairs x 2 halves);
// blocks 32-159 (2x512-thr units) compute pre-activations for chunk c.
// ===========================================================================
__global__ __launch_bounds__(1024) void k_fused(int c,
    const float* __restrict__ x, const float* __restrict__ dl,
    const float* __restrict__ mk, const float* __restrict__ xf,
    const float* __restrict__ bz, const float* __restrict__ br, const float* __restrict__ bc,
    const float* __restrict__ Bgh,
    const float* __restrict__ Wgx, const float* __restrict__ Bgx,
    const short* __restrict__ PW, const short* __restrict__ PG,
    const short* __restrict__ PUc, const unsigned char* __restrict__ PU8,
    bfu* __restrict__ buf0, bfu* __restrict__ buf1, float* __restrict__ hws,
    float* __restrict__ zx, float* __restrict__ cx, u32* __restrict__ flags)
{
    __shared__ char sm[32768];
    if (blockIdx.x < 32) {
        if (c == 0) return;
        const bfu* pre = (c & 1) ? buf0 : buf1;    // chunk c-1 lives in buf[(c-1)&1]
        int p = blockIdx.x & 15, hb = blockIdx.x >> 4;
        scan_block(sm, p, hb, (c - 1) * CH, pre, PUc, PU8, hws, zx, cx, flags);
    } else {
        if (c >= NCH) return;
        int unit = ((int)blockIdx.x - 32) * 2 + (threadIdx.x >> 9);
        if (unit >= B_) return;
        bfu* dst = (c & 1) ? buf1 : buf0;           // chunk c -> buf[c&1]
        k1_unit(sm + (threadIdx.x >> 9) * 12288, unit, c * CH,
                x, dl, mk, xf, bz, br, bc, Bgh, Wgx, Bgx, PW, PG,
                dst, dst + SLOTS, dst + 2 * SLOTS, dst + 3 * SLOTS);
    }
}

// ===========================================================================
// k3: BatchNorm(eval) + decoder GEMV + log_softmax.
// ===========================================================================
__global__ __launch_bounds__(128) void k3_out(
    const float* __restrict__ hws,
    const float* __restrict__ dW, const float* __restrict__ db,
    const float* __restrict__ bng, const float* __restrict__ bnb,
    float* __restrict__ out)
{
    __shared__ float hb[H_];
    __shared__ float red[O_];
    const int tid = threadIdx.x;
    const int b = blockIdx.x;
    const float s = 0.9999950000374997f;   // 1/sqrt(1 + 1e-5)
    for (int k = tid; k < H_; k += O_) {
        float v = hws[(size_t)b * H_ + k] * s * bng[k] + bnb[k];
        hb[k] = v;
        out[B_ * O_ + (size_t)b * H_ + k] = v;
    }
    __syncthreads();
    float acc = db[tid];
    #pragma unroll 4
    for (int k = 0; k < H_; ++k) acc += hb[k] * dW[(size_t)k * O_ + tid];
    red[tid] = acc;
    __syncthreads();
    for (int sh = 64; sh > 0; sh >>= 1) {
        if (tid < sh) red[tid] = fmaxf(red[tid], red[tid + sh]);
        __syncthreads();
    }
    float mx = red[0];
    __syncthreads();
    red[tid] = __expf(acc - mx);
    __syncthreads();
    for (int sh = 64; sh > 0; sh >>= 1) {
        if (tid < sh) red[tid] += red[tid + sh];
        __syncthreads();
    }
    float lse = __logf(red[0]) + mx;
    out[(size_t)b * O_ + tid] = acc - lse;
}

extern "C" void kernel_launch(void* const* d_in, const int* in_sizes, int n_in,
                              void* d_out, int out_size, void* d_ws, size_t ws_size,
                              hipStream_t stream)
{
    (void)in_sizes; (void)n_in; (void)out_size; (void)ws_size;
    const float* x   = (const float*)d_in[0];
    const float* dl  = (const float*)d_in[1];
    const float* m   = (const float*)d_in[2];
    const float* xf  = (const float*)d_in[3];
    const float* Wr  = (const float*)d_in[4];
    const float* Ur  = (const float*)d_in[5];
    const float* Vr  = (const float*)d_in[6];
    const float* br  = (const float*)d_in[7];
    const float* Wz  = (const float*)d_in[8];
    const float* Uz  = (const float*)d_in[9];
    const float* Vz  = (const float*)d_in[10];
    const float* bz  = (const float*)d_in[11];
    const float* Wc  = (const float*)d_in[12];
    const float* Uc  = (const float*)d_in[13];
    const float* Vc  = (const float*)d_in[14];
    const float* bc  = (const float*)d_in[15];
    const float* Wgx = (const float*)d_in[16];
    const float* Bgx = (const float*)d_in[17];
    const float* Wgh = (const float*)d_in[18];
    const float* Bgh = (const float*)d_in[19];
    const float* dW  = (const float*)d_in[20];
    const float* db  = (const float*)d_in[21];
    const float* bng = (const float*)d_in[22];
    const float* bnb = (const float*)d_in[23];

    char* p = (char*)d_ws;
    short* PW = (short*)p;              p += (size_t)3 * 256 * 64 * 8 * 2;   // 768 KB
    short* PG = (short*)p;              p += (size_t)128 * 64 * 8 * 2;       // 128 KB
    short* PUc = (short*)p;             p += (size_t)512 * 64 * 8 * 2;       // 512 KB
    unsigned char* PU8 = (unsigned char*)p; p += (size_t)1024 * 64 * 8;      // 512 KB
    bfu* buf0 = (bfu*)p;                p += 4 * SLOTS * 2;                  // 16 MB
    bfu* buf1 = (bfu*)p;                p += 4 * SLOTS * 2;                  // 16 MB
    float* hws = (float*)p;             p += (size_t)B_ * H_ * 4;            // 512 KB
    float* zx  = (float*)p;             p += (size_t)16 * 2 * 2 * 4096 * 4;  // 1 MB
    float* cx  = (float*)p;             p += (size_t)16 * 2 * 2 * 8192 * 4;  // 2 MB
    u32* flags = (u32*)p;                                                    // 4 KB

    hipMemsetAsync(hws, 0, (size_t)B_ * H_ * sizeof(float), stream);
    hipMemsetAsync(flags, 0, (size_t)32 * 32 * sizeof(u32), stream);
    k_pack<<<dim3(608), dim3(256), 0, stream>>>(Wz, Wr, Wc, Vz, Vr, Vc, Wgh,
                                                Uz, Ur, Uc, PW, PG, PUc, PU8);
    for (int c = 0; c <= NCH; ++c) {
        k_fused<<<dim3(160), dim3(1024), 0, stream>>>(c,
            x, dl, m, xf, bz, br, bc, Bgh, Wgx, Bgx,
            PW, PG, PUc, PU8, buf0, buf1, hws, zx, cx, flags);
    }
    k3_out<<<dim3(B_), dim3(O_), 0, stream>>>(hws, dW, db, bng, bnb, (float*)d_out);
}

// Round 10
// 2387.685 us; speedup vs baseline: 2.2572x; 1.3369x over previous
//
#include <hip/hip_runtime.h>
#include <stdint.h>

typedef float  f32x4 __attribute__((ext_vector_type(4)));
typedef short  s16x8 __attribute__((ext_vector_type(8)));
typedef unsigned int u32;
typedef unsigned long long u64;
typedef unsigned short bfu;
typedef long long i64;

#define B_ 256
#define T_ 256
#define I_ 128
#define H_ 512
#define O_ 128
#define CH 16
#define NCH (T_ / CH)
#define SLOTS ((size_t)CH * B_ * H_)   // elems per bf16 pre-array

__device__ __forceinline__ bfu f2b(float f) {
    u32 u = __float_as_uint(f);
    u += 0x7fffu + ((u >> 16) & 1u);
    return (bfu)(u >> 16);
}
__device__ __forceinline__ float b2f(bfu b) { return __uint_as_float(((u32)b) << 16); }

// fast reciprocal (v_rcp_f32, ~1e-5 rel err — negligible vs fp8 gate noise)
#if defined(__has_builtin)
#if __has_builtin(__builtin_amdgcn_rcpf)
#define RCPF(x) __builtin_amdgcn_rcpf(x)
#endif
#endif
#ifndef RCPF
#define RCPF(x) (1.f / (x))
#endif
__device__ __forceinline__ float sigf(float x) { return RCPF(1.f + __expf(-x)); }
__device__ __forceinline__ float tanhfast(float x) { return 1.f - 2.f * RCPF(__expf(2.f * x) + 1.f); }
__device__ __forceinline__ u64 pk2(float a, float b) {
    return (u64)__float_as_uint(a) | ((u64)__float_as_uint(b) << 32);
}
__device__ __forceinline__ float lo2(u64 v) { return __uint_as_float((u32)v); }
__device__ __forceinline__ float hi2(u64 v) { return __uint_as_float((u32)(v >> 32)); }

// software float -> OCP e4m3fn, RNE, saturating
__device__ __forceinline__ unsigned char f2e4m3(float f) {
    u32 u = __float_as_uint(f);
    u32 s = (u >> 24) & 0x80u;
    u &= 0x7fffffffu;
    if (u >= 0x43e00000u) return (unsigned char)(s | 0x7eu);    // >= 448 -> sat
    if (u < 0x3c800000u) {                                       // < 2^-6 -> subnormal
        int m = __float2int_rn(__uint_as_float(u) * 512.f);
        if (m >= 8) return (unsigned char)(s | 0x08u);
        return (unsigned char)(s | (u32)m);
    }
    u += 0x7ffffu + ((u >> 20) & 1u);                            // RNE at bit 20
    u32 e8 = ((u >> 23) & 0xffu) - 120u;                         // bias 127 -> 7
    return (unsigned char)(s | (e8 << 3) | ((u >> 20) & 7u));
}

// hardware fp8 conversion where available (gfx950: OCP e4m3, RNE — same
// rounding as the software path; inputs here are bounded |x| <= 64 < 448)
#if defined(__has_builtin)
#if __has_builtin(__builtin_amdgcn_cvt_pk_fp8_f32)
#define HW_FP8 1
#endif
#endif
#ifdef HW_FP8
__device__ __forceinline__ unsigned char f2e4m3_fast(float f) {
    return (unsigned char)(__builtin_amdgcn_cvt_pk_fp8_f32(f, f, 0, 0) & 0xffu);
}
#else
#define f2e4m3_fast f2e4m3
#endif

// ===========================================================================
// k_pack: weights -> MFMA B-fragment order.
// frag 16x16x32: lane L holds B[k = kt*32 + (L>>4)*8 + j][n = nt*16 + (L&15)].
// PW bf16 (W|V per gate), PG bf16 (Wgh), PUc bf16 (Uc), PU8 fp8 (Uz,Ur x32).
// ===========================================================================
__global__ __launch_bounds__(256) void k_pack(
    const float* __restrict__ Wz, const float* __restrict__ Wr, const float* __restrict__ Wc,
    const float* __restrict__ Vz, const float* __restrict__ Vr, const float* __restrict__ Vc,
    const float* __restrict__ Wgh,
    const float* __restrict__ Uz, const float* __restrict__ Ur, const float* __restrict__ Uc,
    short* __restrict__ PW, short* __restrict__ PG, short* __restrict__ PUc,
    unsigned char* __restrict__ PU8)
{
    int wv = blockIdx.x * 4 + (threadIdx.x >> 6);
    int L = threadIdx.x & 63;
    if (wv >= 2432) return;
    int koff = (L >> 4) << 3;
    int ncol;
    if (wv < 768) {                       // PW: gate x (kt<4:W, kt>=4:V)
        int g = wv >> 8, rem = wv & 255;
        int kt = rem >> 5; ncol = (rem & 31) * 16 + (L & 15);
        const float* src = (kt < 4) ? (g == 0 ? Wz : g == 1 ? Wr : Wc)
                                    : (g == 0 ? Vz : g == 1 ? Vr : Vc);
        int kbase = (kt & 3) * 32 + koff;
        s16x8 v;
        #pragma unroll
        for (int j = 0; j < 8; ++j) v[j] = (short)f2b(src[(kbase + j) * H_ + ncol]);
        *(s16x8*)&PW[((size_t)(g * 256 + rem) * 64 + L) * 8] = v;
    } else if (wv < 896) {                // PG
        int rem = wv - 768;
        ncol = (rem & 31) * 16 + (L & 15);
        int kbase = (rem >> 5) * 32 + koff;
        s16x8 v;
        #pragma unroll
        for (int j = 0; j < 8; ++j) v[j] = (short)f2b(Wgh[(kbase + j) * H_ + ncol]);
        *(s16x8*)&PG[((size_t)rem * 64 + L) * 8] = v;
    } else if (wv < 1408) {               // PUc bf16
        int rem = wv - 896;               // kt*32+nt, kt 0..15
        ncol = (rem & 31) * 16 + (L & 15);
        int kbase = (rem >> 5) * 32 + koff;
        s16x8 v;
        #pragma unroll
        for (int j = 0; j < 8; ++j) v[j] = (short)f2b(Uc[(kbase + j) * H_ + ncol]);
        *(s16x8*)&PUc[((size_t)rem * 64 + L) * 8] = v;
    } else {                              // PU8: Uz, Ur scaled x32, e4m3
        int rem = wv - 1408;              // g*512 + kt*32 + nt
        int g = rem >> 9, r2 = rem & 511;
        ncol = (r2 & 31) * 16 + (L & 15);
        int kbase = (r2 >> 5) * 32 + koff;
        const float* src = (g == 0) ? Uz : Ur;
        unsigned char* d = PU8 + ((size_t)rem * 64 + L) * 8;
        #pragma unroll
        for (int j = 0; j < 8; ++j) d[j] = f2e4m3(src[(kbase + j) * H_ + ncol] * 32.f);
    }
}

// ===========================================================================
// k1 unit: input-side projections for one batch row b, 16 timesteps.
// 512 threads (8 waves x 64 cols). bf16 outputs, layout [tl][b][H].
// ===========================================================================
__device__ void k1_unit(char* sm, int b, int t0,
    const float* __restrict__ x, const float* __restrict__ dl,
    const float* __restrict__ mk, const float* __restrict__ xf,
    const float* __restrict__ bz, const float* __restrict__ br, const float* __restrict__ bc,
    const float* __restrict__ Bgh,
    const float* __restrict__ Wgx, const float* __restrict__ Bgx,
    const short* __restrict__ PW, const short* __restrict__ PG,
    bfu* __restrict__ pz, bfu* __restrict__ pr, bfu* __restrict__ pc, bfu* __restrict__ gm)
{
    short* Abuf = (short*)sm;             // 12 KB: [kt 0..11][lane][8]
    const int t = threadIdx.x & 511;
    const int L = t & 63, w = t >> 6;

    for (int cc = t; cc < 12 * 64; cc += 512) {
        int Ls = cc & 63, kt = cc >> 6;
        int tl = Ls & 15, q = Ls >> 4;
        int gbase = (b * T_ + t0 + tl) * I_;
        s16x8 v;
        if (kt < 4) {
            int kb = kt * 32 + q * 8;
            f32x4 m0 = *(const f32x4*)&mk[gbase + kb], m1 = *(const f32x4*)&mk[gbase + kb + 4];
            f32x4 d0 = *(const f32x4*)&dl[gbase + kb], d1 = *(const f32x4*)&dl[gbase + kb + 4];
            f32x4 f0 = *(const f32x4*)&xf[gbase + kb], f1 = *(const f32x4*)&xf[gbase + kb + 4];
            f32x4 x0 = *(const f32x4*)&x[gbase + kb],  x1 = *(const f32x4*)&x[gbase + kb + 4];
            #pragma unroll
            for (int j = 0; j < 8; ++j) {
                int k = kb + j;
                float mv = (j < 4) ? m0[j] : m1[j - 4];
                float dv = (j < 4) ? d0[j] : d1[j - 4];
                float fv = (j < 4) ? f0[j] : f1[j - 4];
                float xv = (j < 4) ? x0[j] : x1[j - 4];
                float dx = dv * Wgx[k] + Bgx[k];
                float xr = dx * fv + (1.f - dx) * 0.001f;
                v[j] = (short)f2b((mv > 0.5f) ? xr : xv);
            }
        } else if (kt < 8) {
            int kb = (kt - 4) * 32 + q * 8;
            f32x4 m0 = *(const f32x4*)&mk[gbase + kb], m1 = *(const f32x4*)&mk[gbase + kb + 4];
            #pragma unroll
            for (int j = 0; j < 8; ++j) v[j] = (short)f2b(1.f - ((j < 4) ? m0[j] : m1[j - 4]));
        } else {
            int kb = (kt - 8) * 32 + q * 8;
            f32x4 m0 = *(const f32x4*)&mk[gbase + kb], m1 = *(const f32x4*)&mk[gbase + kb + 4];
            #pragma unroll
            for (int j = 0; j < 8; ++j) v[j] = (short)f2b((j < 4) ? m0[j] : m1[j - 4]);
        }
        *(s16x8*)&Abuf[(size_t)cc * 8] = v;
    }
    __syncthreads();

    const s16x8* PWf = (const s16x8*)PW;
    const s16x8* PGf = (const s16x8*)PG;

    for (int g = 0; g < 3; ++g) {
        f32x4 acc[4];
        #pragma unroll
        for (int nt = 0; nt < 4; ++nt) acc[nt] = (f32x4)0.f;
        for (int kt = 0; kt < 8; ++kt) {
            s16x8 a = *(const s16x8*)&Abuf[(kt * 64 + L) * 8];
            const s16x8* pw = PWf + ((size_t)(g * 256 + kt * 32 + w * 4) * 64 + L);
            #pragma unroll
            for (int nt = 0; nt < 4; ++nt)
                acc[nt] = __builtin_amdgcn_mfma_f32_16x16x32_bf16(a, pw[(size_t)nt * 64], acc[nt], 0, 0, 0);
        }
        const float* bias = (g == 0) ? bz : (g == 1) ? br : bc;
        bfu* dst = (g == 0) ? pz : (g == 1) ? pr : pc;
        #pragma unroll
        for (int nt = 0; nt < 4; ++nt) {
            int n = w * 64 + nt * 16 + (L & 15);
            float bv = bias[n];
            #pragma unroll
            for (int reg = 0; reg < 4; ++reg) {
                int tl = (L >> 4) * 4 + reg;
                dst[(size_t)(tl * B_ + b) * H_ + n] = f2b(acc[nt][reg] + bv);
            }
        }
    }
    {
        f32x4 acc[4];
        #pragma unroll
        for (int nt = 0; nt < 4; ++nt) acc[nt] = (f32x4)0.f;
        for (int kk = 0; kk < 4; ++kk) {
            s16x8 a = *(const s16x8*)&Abuf[((8 + kk) * 64 + L) * 8];
            const s16x8* pg = PGf + ((size_t)(kk * 32 + w * 4) * 64 + L);
            #pragma unroll
            for (int nt = 0; nt < 4; ++nt)
                acc[nt] = __builtin_amdgcn_mfma_f32_16x16x32_bf16(a, pg[(size_t)nt * 64], acc[nt], 0, 0, 0);
        }
        #pragma unroll
        for (int nt = 0; nt < 4; ++nt) {
            int n = w * 64 + nt * 16 + (L & 15);
            float bv = Bgh[n];
            #pragma unroll
            for (int reg = 0; reg < 4; ++reg) {
                int tl = (L >> 4) * 4 + reg;
                gm[(size_t)(tl * B_ + b) * H_ + n] = f2b(__expf(-fmaxf(acc[nt][reg] + bv, 0.f)));
            }
        }
    }
}

// ===========================================================================
// scan block (R10 = R9 + weight LDS cache): pair p rows [16p,16p+16); half
// hb owns z/r cols [hb*256,+256) and c-GEMM K-rows [hb*256,+256).
// New vs R9: each wave caches its phase-A weight fragments for kt 0..6
// (14 x 512 B = 7 KB/wave, 112 KB/block) in LDS once per dispatch (per-wave
// private -> no barrier needed), cutting phase-A L2 traffic 256->144 KB/step.
// Gates use v_rcp (RCPF) instead of IEEE division.
// Sync protocol identical to R6/R9: 4 block barriers, tid0 flag + poll.
// ===========================================================================
__device__ void scan_block(char* sm, int p, int hb, int base, const bfu* __restrict__ pre,
                           const short* __restrict__ PUc, const unsigned char* __restrict__ PU8,
                           float* __restrict__ hws,
                           float* __restrict__ zx, float* __restrict__ cx,
                           u32* __restrict__ flags)
{
    char*  Abf8 = sm;                        // 8 KB fp8 A-fragments [16 kt][64][8] (full K)
    short* Apbf = (short*)(sm + 8192);       // 8 KB bf16 (A*r)-fragments, own K-half
    float* zl   = (float*)(sm + 16384);      // 16 KB f32 col-major [256 cols][16 rows]: own z
    u64*  wlds  = (u64*)(sm + 32768);        // 112 KB phase-A weight cache, kt 0..6
    const bfu* pz = pre;
    const bfu* pr = pre + SLOTS;
    const bfu* pc = pre + 2 * SLOTS;
    const bfu* gm = pre + 3 * SLOTS;
    const int tid = threadIdx.x, L = tid & 63, w = tid >> 6;
    const int b0 = p * 16;
    const i64* PU8q = (const i64*)PU8;
    const s16x8* PUcf = (const s16x8*)PUc;
    const float INV = 4.8828125e-4f;        // 1/2048
    const int BH = B_ * H_;                  // per-timestep preact stride

    int nn[2], ktq[2], lsh[2], j2;
    #pragma unroll
    for (int nt = 0; nt < 2; ++nt) {
        nn[nt] = w * 32 + nt * 16 + (L & 15);
        ktq[nt] = nn[nt] >> 5;
        lsh[nt] = ((nn[nt] >> 3) & 3) << 4;
    }
    j2 = nn[0] & 7;
    const int row0 = (L >> 4) * 4;
    const int ph = w >> 3;                   // half that this wave's nn cols live in
    const bool isR = (ph == hb);             // r/build wave group
    int lc[2], pa_col[2];
    #pragma unroll
    for (int nt = 0; nt < 2; ++nt) {
        lc[nt] = nn[nt] & 255;
        pa_col[nt] = hb * 256 + lc[nt];
    }
    const int tbase = (isR ? 512 : 0) + hb * 16 + (w & 7) * 2;

    // ---- hoisted loop-invariant bases ----
    const i64*   wp  = PU8q + (size_t)tbase * 64 + L;                    // phase-A weights
    const s16x8* cwp = PUcf + ((size_t)(hb * 8) * 32 + w * 2) * 64 + L;  // c weights
    const bfu* srcA = isR ? pr : pz;
    const bfu* paB[2]; const bfu* pcB[2]; const bfu* gmB[2];
    #pragma unroll
    for (int nt = 0; nt < 2; ++nt) {
        paB[nt] = srcA + (size_t)(b0 + row0) * H_ + pa_col[nt];
        pcB[nt] = pc   + (size_t)(b0 + row0) * H_ + nn[nt];
        gmB[nt] = gm   + (size_t)(b0 + row0) * H_ + nn[nt];
    }
    int ixc[2], izc[2];
    #pragma unroll
    for (int nt = 0; nt < 2; ++nt) {
        ixc[nt] = (nn[nt] * 16 + row0) >> 1;
        izc[nt] = (lc[nt] * 16 + row0) >> 1;
    }

    // ---- per-wave weight cache: kt 0..6 (14 x 512 B per wave) ----
    // Same wave writes & reads its own region -> wave-coherent, no barrier.
    u64* wl = wlds + (size_t)w * 14 * 64 + L;
    #pragma unroll
    for (int kt = 0; kt < 7; ++kt) {
        wl[(kt * 2) * 64]     = (u64)wp[(size_t)kt * 2048];
        wl[(kt * 2 + 1) * 64] = (u64)wp[(size_t)kt * 2048 + 64];
    }

    float* zxO0 = zx + (size_t)(p * 2 + hb) * 2 * 4096;
    float* cxO0 = cx + (size_t)(p * 2 + hb) * 2 * 8192;
    float* zxP0 = zx + (size_t)(p * 2 + (1 - hb)) * 2 * 4096;
    float* cxP0 = cx + (size_t)(p * 2 + (1 - hb)) * 2 * 8192;
    u32* flagO = flags + (size_t)(p * 2 + hb) * 32;
    u32* flagP = flags + (size_t)(p * 2 + (1 - hb)) * 32;

    float A32[2][4];
    #pragma unroll
    for (int nt = 0; nt < 2; ++nt)
        #pragma unroll
        for (int reg = 0; reg < 4; ++reg) {
            int row = row0 + reg;
            float h = hws[(size_t)(b0 + row) * H_ + nn[nt]];
            float gv = b2f(gmB[nt][reg * H_]);                     // gm(tl=0)
            float A = gv * h;
            A32[nt][reg] = A;
            Abf8[(ktq[nt] * 64 + (row | lsh[nt])) * 8 + j2] = f2e4m3_fast(A * 64.f);
        }
    __syncthreads();

    // phase-A pre-activations for tl=0 (later steps prefetched in the window)
    float lpa[2][4];
    #pragma unroll
    for (int nt = 0; nt < 2; ++nt)
        #pragma unroll
        for (int reg = 0; reg < 4; ++reg)
            lpa[nt][reg] = b2f(paB[nt][reg * H_]);

    for (int tl = 0; tl < CH; ++tl) {
        const int S = base + tl;
        const int par = S & 1;
        u64* zxOq = (u64*)(par ? zxO0 + 4096 : zxO0);
        u64* cxOq = (u64*)(par ? cxO0 + 8192 : cxO0);
        const u64* zxPq = (const u64*)(par ? zxP0 + 4096 : zxP0);
        const u64* cxPq = (const u64*)(par ? cxP0 + 8192 : cxP0);
        const int tln = (tl + 1 < CH) ? tl + 1 : tl;
        const int off  = tl * BH;            // uniform (SALU) offsets
        const int offn = tln * BH;

        // ---- phase A: fp8 GEMM, 2 tiles/wave (z for z-group, r for isR);
        //      kt 0..6 weights from LDS cache, kt 7..15 streamed from L2 ----
        f32x4 a0 = (f32x4)0.f, a1 = (f32x4)0.f;
        #pragma unroll
        for (int kt = 0; kt < 16; ++kt) {
            i64 a8 = *(const i64*)&Abf8[(kt * 64 + L) * 8];
            i64 w0, w1;
            if (kt < 7) {
                w0 = (i64)wl[(kt * 2) * 64];
                w1 = (i64)wl[(kt * 2 + 1) * 64];
            } else {
                w0 = wp[(size_t)kt * 2048];
                w1 = wp[(size_t)kt * 2048 + 64];
            }
            a0 = __builtin_amdgcn_mfma_f32_16x16x32_fp8_fp8(a8, w0, a0, 0, 0, 0);
            a1 = __builtin_amdgcn_mfma_f32_16x16x32_fp8_fp8(a8, w1, a1, 0, 0, 0);
        }
        if (isR) {
            // r in registers -> fold the (A*r) build directly into phase A
            #pragma unroll
            for (int reg = 0; reg < 4; ++reg) {
                float rg0 = sigf(a0[reg] * INV + lpa[0][reg]);
                float rg1 = sigf(a1[reg] * INV + lpa[1][reg]);
                int m = row0 + reg;
                Apbf[((lc[0] >> 5) * 64 + (m | lsh[0])) * 8 + j2] = (short)f2b(A32[0][reg] * rg0);
                Apbf[((lc[1] >> 5) * 64 + (m | lsh[1])) * 8 + j2] = (short)f2b(A32[1][reg] * rg1);
            }
        } else {
            // z -> zl LDS (col-major) + export (col-major, coalesced)
            f32x4 zq0, zq1;
            #pragma unroll
            for (int reg = 0; reg < 4; ++reg) {
                zq0[reg] = sigf(a0[reg] * INV + lpa[0][reg]);
                zq1[reg] = sigf(a1[reg] * INV + lpa[1][reg]);
            }
            *(f32x4*)&zl[lc[0] * 16 + row0] = zq0;
            *(f32x4*)&zl[lc[1] * 16 + row0] = zq1;
            __hip_atomic_store(&zxOq[izc[0]],     pk2(zq0[0], zq0[1]), __ATOMIC_RELAXED, __HIP_MEMORY_SCOPE_AGENT);
            __hip_atomic_store(&zxOq[izc[0] + 1], pk2(zq0[2], zq0[3]), __ATOMIC_RELAXED, __HIP_MEMORY_SCOPE_AGENT);
            __hip_atomic_store(&zxOq[izc[1]],     pk2(zq1[0], zq1[1]), __ATOMIC_RELAXED, __HIP_MEMORY_SCOPE_AGENT);
            __hip_atomic_store(&zxOq[izc[1] + 1], pk2(zq1[2], zq1[3]), __ATOMIC_RELAXED, __HIP_MEMORY_SCOPE_AGENT);
        }
        __syncthreads();   // (1) Apbf + zl ready (z exports drained here too)

        // ---- c bf16 GEMM: all cols, own K-half ----
        f32x4 ac[2];
        ac[0] = (f32x4)0.f; ac[1] = (f32x4)0.f;
        #pragma unroll 4
        for (int kk = 0; kk < 8; ++kk) {
            s16x8 a = *(const s16x8*)&Apbf[(kk * 64 + L) * 8];
            s16x8 bc0 = cwp[(size_t)kk * 2048];
            s16x8 bc1 = cwp[(size_t)kk * 2048 + 64];
            ac[0] = __builtin_amdgcn_mfma_f32_16x16x32_bf16(a, bc0, ac[0], 0, 0, 0);
            ac[1] = __builtin_amdgcn_mfma_f32_16x16x32_bf16(a, bc1, ac[1], 0, 0, 0);
        }
        // col-major export of c-partials (2 u64 per tile, coalesced)
        #pragma unroll
        for (int nt = 0; nt < 2; ++nt) {
            __hip_atomic_store(&cxOq[ixc[nt]],     pk2(ac[nt][0], ac[nt][1]), __ATOMIC_RELAXED, __HIP_MEMORY_SCOPE_AGENT);
            __hip_atomic_store(&cxOq[ixc[nt] + 1], pk2(ac[nt][2], ac[nt][3]), __ATOMIC_RELAXED, __HIP_MEMORY_SCOPE_AGENT);
        }
        __syncthreads();   // (2) all waves' exports drained (vmcnt 0 before barrier)
        if (tid == 0)
            __hip_atomic_store(flagO, (u32)(S + 1), __ATOMIC_RELEASE, __HIP_MEMORY_SCOPE_AGENT);

        // ---- prefetch update operands (this tl) + phase-A preacts (next tl);
        //      latency hides under the partner round-trip ----
        float lpcv[2][4], lgmv[2][4];
        #pragma unroll
        for (int nt = 0; nt < 2; ++nt)
            #pragma unroll
            for (int reg = 0; reg < 4; ++reg) {
                lpcv[nt][reg] = b2f(pcB[nt][off + reg * H_]);
                lgmv[nt][reg] = b2f(gmB[nt][offn + reg * H_]);
                lpa[nt][reg]  = b2f(paB[nt][offn + reg * H_]);
            }

        if (tid == 0) {
            while (__hip_atomic_load(flagP, __ATOMIC_RELAXED, __HIP_MEMORY_SCOPE_AGENT) < (u32)(S + 1))
                __builtin_amdgcn_s_sleep(1);
        }
        __syncthreads();   // (3) partner data ready

        // ---- import partner data direct to registers + state update ----
        #pragma unroll
        for (int nt = 0; nt < 2; ++nt) {
            u64 c0 = __hip_atomic_load(&cxPq[ixc[nt]],     __ATOMIC_RELAXED, __HIP_MEMORY_SCOPE_AGENT);
            u64 c1 = __hip_atomic_load(&cxPq[ixc[nt] + 1], __ATOMIC_RELAXED, __HIP_MEMORY_SCOPE_AGENT);
            float cpe[4] = { lo2(c0), hi2(c0), lo2(c1), hi2(c1) };
            float zg[4];
            if (isR) {
                f32x4 zv = *(const f32x4*)&zl[lc[nt] * 16 + row0];
                zg[0] = zv[0]; zg[1] = zv[1]; zg[2] = zv[2]; zg[3] = zv[3];
            } else {
                u64 z0 = __hip_atomic_load(&zxPq[izc[nt]],     __ATOMIC_RELAXED, __HIP_MEMORY_SCOPE_AGENT);
                u64 z1 = __hip_atomic_load(&zxPq[izc[nt] + 1], __ATOMIC_RELAXED, __HIP_MEMORY_SCOPE_AGENT);
                zg[0] = lo2(z0); zg[1] = hi2(z0); zg[2] = lo2(z1); zg[3] = hi2(z1);
            }
            #pragma unroll
            for (int reg = 0; reg < 4; ++reg) {
                int m = row0 + reg;
                float cc = tanhfast(ac[nt][reg] + cpe[reg] + lpcv[nt][reg]);
                float hn = (1.f - zg[reg]) * A32[nt][reg] + zg[reg] * cc;
                if (tl < CH - 1) {
                    float An = lgmv[nt][reg] * hn;
                    A32[nt][reg] = An;
                    Abf8[(ktq[nt] * 64 + (m | lsh[nt])) * 8 + j2] = f2e4m3_fast(An * 64.f);
                } else if (isR) {
                    hws[(size_t)(b0 + m) * H_ + nn[nt]] = hn;
                }
            }
        }
        __syncthreads();   // (4) Abf8/zl/Apbf safe to overwrite next step
    }
}

// ===========================================================================
// fused launch: blocks 0-31 scan chunk c-1 (16 pairs x 2 halves);
// blocks 32-159 (2x512-thr units) compute pre-activations for chunk c.
// ===========================================================================
__global__ __launch_bounds__(1024) void k_fused(int c,
    const float* __restrict__ x, const float* __restrict__ dl,
    const float* __restrict__ mk, const float* __restrict__ xf,
    const float* __restrict__ bz, const float* __restrict__ br, const float* __restrict__ bc,
    const float* __restrict__ Bgh,
    const float* __restrict__ Wgx, const float* __restrict__ Bgx,
    const short* __restrict__ PW, const short* __restrict__ PG,
    const short* __restrict__ PUc, const unsigned char* __restrict__ PU8,
    bfu* __restrict__ buf0, bfu* __restrict__ buf1, float* __restrict__ hws,
    float* __restrict__ zx, float* __restrict__ cx, u32* __restrict__ flags)
{
    __shared__ char sm[147456];
    if (blockIdx.x < 32) {
        if (c == 0) return;
        const bfu* pre = (c & 1) ? buf0 : buf1;    // chunk c-1 lives in buf[(c-1)&1]
        int p = blockIdx.x & 15, hb = blockIdx.x >> 4;
        scan_block(sm, p, hb, (c - 1) * CH, pre, PUc, PU8, hws, zx, cx, flags);
    } else {
        if (c >= NCH) return;
        int unit = ((int)blockIdx.x - 32) * 2 + (threadIdx.x >> 9);
        if (unit >= B_) return;
        bfu* dst = (c & 1) ? buf1 : buf0;           // chunk c -> buf[c&1]
        k1_unit(sm + (threadIdx.x >> 9) * 12288, unit, c * CH,
                x, dl, mk, xf, bz, br, bc, Bgh, Wgx, Bgx, PW, PG,
                dst, dst + SLOTS, dst + 2 * SLOTS, dst + 3 * SLOTS);
    }
}

// ===========================================================================
// k3: BatchNorm(eval) + decoder GEMV + log_softmax.
// ===========================================================================
__global__ __launch_bounds__(128) void k3_out(
    const float* __restrict__ hws,
    const float* __restrict__ dW, const float* __restrict__ db,
    const float* __restrict__ bng, const float* __restrict__ bnb,
    float* __restrict__ out)
{
    __shared__ float hb[H_];
    __shared__ float red[O_];
    const int tid = threadIdx.x;
    const int b = blockIdx.x;
    const float s = 0.9999950000374997f;   // 1/sqrt(1 + 1e-5)
    for (int k = tid; k < H_; k += O_) {
        float v = hws[(size_t)b * H_ + k] * s * bng[k] + bnb[k];
        hb[k] = v;
        out[B_ * O_ + (size_t)b * H_ + k] = v;
    }
    __syncthreads();
    float acc = db[tid];
    #pragma unroll 4
    for (int k = 0; k < H_; ++k) acc += hb[k] * dW[(size_t)k * O_ + tid];
    red[tid] = acc;
    __syncthreads();
    for (int sh = 64; sh > 0; sh >>= 1) {
        if (tid < sh) red[tid] = fmaxf(red[tid], red[tid + sh]);
        __syncthreads();
    }
    float mx = red[0];
    __syncthreads();
    red[tid] = __expf(acc - mx);
    __syncthreads();
    for (int sh = 64; sh > 0; sh >>= 1) {
        if (tid < sh) red[tid] += red[tid + sh];
        __syncthreads();
    }
    float lse = __logf(red[0]) + mx;
    out[(size_t)b * O_ + tid] = acc - lse;
}

extern "C" void kernel_launch(void* const* d_in, const int* in_sizes, int n_in,
                              void* d_out, int out_size, void* d_ws, size_t ws_size,
                              hipStream_t stream)
{
    (void)in_sizes; (void)n_in; (void)out_size; (void)ws_size;
    const float* x   = (const float*)d_in[0];
    const float* dl  = (const float*)d_in[1];
    const float* m   = (const float*)d_in[2];
    const float* xf  = (const float*)d_in[3];
    const float* Wr  = (const float*)d_in[4];
    const float* Ur  = (const float*)d_in[5];
    const float* Vr  = (const float*)d_in[6];
    const float* br  = (const float*)d_in[7];
    const float* Wz  = (const float*)d_in[8];
    const float* Uz  = (const float*)d_in[9];
    const float* Vz  = (const float*)d_in[10];
    const float* bz  = (const float*)d_in[11];
    const float* Wc  = (const float*)d_in[12];
    const float* Uc  = (const float*)d_in[13];
    const float* Vc  = (const float*)d_in[14];
    const float* bc  = (const float*)d_in[15];
    const float* Wgx = (const float*)d_in[16];
    const float* Bgx = (const float*)d_in[17];
    const float* Wgh = (const float*)d_in[18];
    const float* Bgh = (const float*)d_in[19];
    const float* dW  = (const float*)d_in[20];
    const float* db  = (const float*)d_in[21];
    const float* bng = (const float*)d_in[22];
    const float* bnb = (const float*)d_in[23];

    char* p = (char*)d_ws;
    short* PW = (short*)p;              p += (size_t)3 * 256 * 64 * 8 * 2;   // 768 KB
    short* PG = (short*)p;              p += (size_t)128 * 64 * 8 * 2;       // 128 KB
    short* PUc = (short*)p;             p += (size_t)512 * 64 * 8 * 2;       // 512 KB
    unsigned char* PU8 = (unsigned char*)p; p += (size_t)1024 * 64 * 8;      // 512 KB
    bfu* buf0 = (bfu*)p;                p += 4 * SLOTS * 2;                  // 16 MB
    bfu* buf1 = (bfu*)p;                p += 4 * SLOTS * 2;                  // 16 MB
    float* hws = (float*)p;             p += (size_t)B_ * H_ * 4;            // 512 KB
    float* zx  = (float*)p;             p += (size_t)16 * 2 * 2 * 4096 * 4;  // 1 MB
    float* cx  = (float*)p;             p += (size_t)16 * 2 * 2 * 8192 * 4;  // 2 MB
    u32* flags = (u32*)p;                                                    // 4 KB

    hipMemsetAsync(hws, 0, (size_t)B_ * H_ * sizeof(float), stream);
    hipMemsetAsync(flags, 0, (size_t)32 * 32 * sizeof(u32), stream);
    k_pack<<<dim3(608), dim3(256), 0, stream>>>(Wz, Wr, Wc, Vz, Vr, Vc, Wgh,
                                                Uz, Ur, Uc, PW, PG, PUc, PU8);
    for (int c = 0; c <= NCH; ++c) {
        k_fused<<<dim3(160), dim3(1024), 0, stream>>>(c,
            x, dl, m, xf, bz, br, bc, Bgh, Wgx, Bgx,
            PW, PG, PUc, PU8, buf0, buf1, hws, zx, cx, flags);
    }
    k3_out<<<dim3(B_), dim3(O_), 0, stream>>>(hws, dW, db, bng, bnb, (float*)d_out);
}